// Round 4
// baseline (277.483 us; speedup 1.0000x reference)
//
#include <hip/hip_runtime.h>
#include <math.h>

// B=64, CLN=32, QL=32, IH=16, IW=16, IDF=8192, CDF=256, SL=128
// input : [64][32][32][16][16] fp32 ; context:[64][256][128] fp32 ; W:[8192][256] fp32
// out0: wc fp32 (16777216) ; out1: attnT [64][128][32] fp32 (262144)
//
// Zero-LDS MFMA pipeline, frag-major pre-swizzled operands.
// k1 uses fp16 hi/lo 3-pass (precision for softmax logits); k3/k4 single fp16.
//  k0: W -> Wth/Wtl (k1 B-operand hi/lo, frag-major) + Wbf (k4 A-operand fp16)
//  k1: tWpart[z][m][c] = targetT @ W   (no LDS/barriers; ZK=8, m-tile 32)
//  k2: reduce partials; logits = tW @ ctx; softmax -> attnT (out1)
//  k3: ctxAqf (k4 B-operand, frag-major fp16) = ctx @ attn
//  k4: wc = W @ ctxA per batch (no LDS/barriers), .view-faithful scatter

#define ZK 8

typedef _Float16 f16x8 __attribute__((ext_vector_type(8)));
typedef float f32x4 __attribute__((ext_vector_type(4)));

// ---------------------------------------------------------------------------
// K0: pre-swizzle W into frag-major fp16 operands. grid(256) x 256 thr.
// Block kb handles d-rows kb*32..kb*32+31, all 256 c.
// ---------------------------------------------------------------------------
__global__ __launch_bounds__(256) void k0_prep(const float* __restrict__ Wm,
                                               _Float16* __restrict__ Wth,
                                               _Float16* __restrict__ Wtl,
                                               _Float16* __restrict__ Wbf) {
    const int kb = blockIdx.x;          // 0..255
    const int t = threadIdx.x;
    __shared__ float tile[32][260];
    {
        const int r = t >> 3;           // 0..31
        const int c0 = (t & 7) * 32;    // 0..224
        const float* src = Wm + (long)(kb * 32 + r) * 256 + c0;
#pragma unroll
        for (int i = 0; i < 8; ++i) {
            float4 v = *(const float4*)(src + i * 4);
            tile[r][c0 + i * 4 + 0] = v.x;
            tile[r][c0 + i * 4 + 1] = v.y;
            tile[r][c0 + i * 4 + 2] = v.z;
            tile[r][c0 + i * 4 + 3] = v.w;
        }
    }
    __syncthreads();
    const int lane = t & 63;
    const int quad = lane >> 4, l15 = lane & 15;
    // Wth/Wtl: k1 B-frag: B[n=c][k=d] ; lane=(c&15)+16*((k>>3)&3), j=k&7
#pragma unroll
    for (int i = 0; i < 4; ++i) {
        int nsub = (t >> 6) * 4 + i;    // 0..15
        f16x8 oh, ol;
#pragma unroll
        for (int j = 0; j < 8; ++j) {
            float f = tile[quad * 8 + j][nsub * 16 + l15];
            _Float16 h = (_Float16)f;
            oh[j] = h;
            ol[j] = (_Float16)(f - (float)h);
        }
        long addr = ((long)(kb * 16 + nsub) * 64 + lane) * 8;
        *(f16x8*)(Wth + addr) = oh;
        *(f16x8*)(Wtl + addr) = ol;
    }
    // Wbf: k4 A-frag: A[m=d][k=c] ; lane=(d&15)+16*((c>>3)&3), j=c&7
#pragma unroll
    for (int i = 0; i < 4; ++i) {
        int comb = (t >> 6) * 4 + i;    // 0..15
        int mbi = comb >> 3;            // 0..1
        int kb4 = comb & 7;             // 0..7
        f16x8 o;
#pragma unroll
        for (int j = 0; j < 8; ++j)
            o[j] = (_Float16)tile[mbi * 16 + l15][kb4 * 32 + quad * 8 + j];
        *(f16x8*)(Wbf + ((long)((kb * 2 + mbi) * 8 + kb4) * 64 + lane) * 8) = o;
    }
}

// ---------------------------------------------------------------------------
// K1: tWpart = targetT @ W, fp16 hi/lo 3-pass. No LDS.
// grid (64 m-tiles of 32, ZK) x 256 thr. Wave tile: 16 m x 128 n.
// ---------------------------------------------------------------------------
__global__ __launch_bounds__(256) void k1_mfma(const float* __restrict__ inp,
                                               const _Float16* __restrict__ Wth,
                                               const _Float16* __restrict__ Wtl,
                                               float* __restrict__ tWpart) {
    const int m0 = blockIdx.x * 32;
    const int kz = blockIdx.y;
    const int t = threadIdx.x;
    const int lane = t & 63, wv = t >> 6;
    const int quad = lane >> 4, l15 = lane & 15;
    const int mi = wv >> 1, ni = wv & 1;

    const int m = m0 + mi * 16 + l15;
    const float* arow = inp + (long)(m >> 5) * 262144 + (long)(m & 31) * 256;

    f32x4 acc[8];
#pragma unroll
    for (int j = 0; j < 8; ++j) acc[j] = (f32x4){0.f, 0.f, 0.f, 0.f};

    for (int it = 0; it < 32; ++it) {
        const int k0 = kz * 1024 + it * 32;
        const float* ap = arow + (long)(k0 >> 8) * 8192 + (k0 & 255) + quad * 8;
        float4 u0 = *(const float4*)(ap);
        float4 u1 = *(const float4*)(ap + 4);
        float ff[8] = {u0.x, u0.y, u0.z, u0.w, u1.x, u1.y, u1.z, u1.w};
        f16x8 ah, al;
#pragma unroll
        for (int j = 0; j < 8; ++j) {
            _Float16 h = (_Float16)ff[j];
            ah[j] = h;
            al[j] = (_Float16)(ff[j] - (float)h);
        }
        const int kb = kz * 32 + it;
        const _Float16* bbase = Wth + ((long)(kb * 16 + ni * 8) * 64 + lane) * 8;
        const _Float16* lbase = Wtl + ((long)(kb * 16 + ni * 8) * 64 + lane) * 8;
#pragma unroll
        for (int j = 0; j < 8; ++j) {
            f16x8 bh = *(const f16x8*)(bbase + (long)j * 512);
            f16x8 bl = *(const f16x8*)(lbase + (long)j * 512);
            acc[j] = __builtin_amdgcn_mfma_f32_16x16x32_f16(ah, bh, acc[j], 0, 0, 0);
            acc[j] = __builtin_amdgcn_mfma_f32_16x16x32_f16(al, bh, acc[j], 0, 0, 0);
            acc[j] = __builtin_amdgcn_mfma_f32_16x16x32_f16(ah, bl, acc[j], 0, 0, 0);
        }
    }
    float* outp = tWpart + (long)kz * 524288;
    const int mbase = m0 + mi * 16 + quad * 4;
#pragma unroll
    for (int j = 0; j < 8; ++j) {
        const int c = ni * 128 + j * 16 + l15;
#pragma unroll
        for (int rg = 0; rg < 4; ++rg)
            outp[(long)(mbase + rg) * 256 + c] = acc[j][rg];
    }
}

// ---------------------------------------------------------------------------
// K2: reduce split-K partials; logits = tW @ ctx[b]; softmax; write attnT.
// grid (8 q-groups of 4, 64 b) x 256 thr. One wave per q row.
// ---------------------------------------------------------------------------
__global__ __launch_bounds__(256) void k2_logits_softmax(const float* __restrict__ tWpart,
                                                         const float* __restrict__ ctx,
                                                         float* __restrict__ attnT) {
    const int qg = blockIdx.x;      // 0..7
    const int b  = blockIdx.y;
    const int t  = threadIdx.x;
    __shared__ float tw4[4][256];
#pragma unroll
    for (int qq = 0; qq < 4; ++qq) {
        const float* p = tWpart + (long)(b * 32 + qg * 4 + qq) * 256 + t;
        float s = 0.f;
#pragma unroll
        for (int z = 0; z < ZK; ++z) s += p[(long)z * 524288];
        tw4[qq][t] = s;
    }
    __syncthreads();
    const int q = t >> 6, lane = t & 63;
    const float* ctxb = ctx + (long)b * 32768 + lane * 2;
    float ax = 0.f, ay = 0.f;
#pragma unroll 4
    for (int c = 0; c < 256; ++c) {
        float tw = tw4[q][c];
        float2 cv = *(const float2*)(ctxb + c * 128);
        ax = fmaf(tw, cv.x, ax);
        ay = fmaf(tw, cv.y, ay);
    }
    float mx = fmaxf(ax, ay);
#pragma unroll
    for (int m = 1; m <= 32; m <<= 1) mx = fmaxf(mx, __shfl_xor(mx, m));
    float ex = expf(ax - mx);
    float ey = expf(ay - mx);
    float sm = ex + ey;
#pragma unroll
    for (int m = 1; m <= 32; m <<= 1) sm += __shfl_xor(sm, m);
    float inv = 1.f / sm;
    ex *= inv; ey *= inv;
    float* o = attnT + (long)b * 4096 + (qg * 4 + q);
    o[(lane * 2 + 0) * 32] = ex;
    o[(lane * 2 + 1) * 32] = ey;
}

// ---------------------------------------------------------------------------
// K3: ctxAqf (frag-major fp16) = ctx @ attn. grid (8 c-chunks, 64 b) x 256.
// Frag addr: [((n>>4)*8 + (c>>5))*64 + (n&15) + 16*((c>>3)&3)]*8 + (c&7)
// ---------------------------------------------------------------------------
__global__ __launch_bounds__(256) void k3_ctxA(const float* __restrict__ ctx,
                                               const float* __restrict__ attnT,
                                               _Float16* __restrict__ ctxAqf) {
    const int cg = blockIdx.x;      // c-chunk of 32
    const int b  = blockIdx.y;
    const int t  = threadIdx.x;
    __shared__ float at[128][32];
    __shared__ float cs[32][132];
#pragma unroll
    for (int i = 0; i < 4; ++i)
        *(float4*)((float*)at + i * 1024 + t * 4) =
            *(const float4*)(attnT + (long)b * 4096 + i * 1024 + t * 4);
#pragma unroll
    for (int i = 0; i < 4; ++i) {
        int idx = i * 256 + t;
        int c = idx >> 5, sseg = (idx & 31) * 4;
        *(float4*)&cs[c][sseg] = *(const float4*)(ctx + (long)b * 32768 + (long)(cg * 32 + c) * 128 + sseg);
    }
    __syncthreads();
    const int c = t >> 3;           // 0..31 (local)
    const int qs = (t & 7) * 4;     // 4 q's
    float4 acc = make_float4(0.f, 0.f, 0.f, 0.f);
#pragma unroll 4
    for (int s = 0; s < 128; ++s) {
        float cv = cs[c][s];
        float4 av = *(const float4*)&at[s][qs];
        acc.x = fmaf(cv, av.x, acc.x);
        acc.y = fmaf(cv, av.y, acc.y);
        acc.z = fmaf(cv, av.z, acc.z);
        acc.w = fmaf(cv, av.w, acc.w);
    }
    const int cglob = cg * 32 + c;
    const long cpart = (long)(cglob >> 5) * 64 + 16 * ((cglob >> 3) & 3);
    float vals[4] = {acc.x, acc.y, acc.z, acc.w};
#pragma unroll
    for (int u = 0; u < 4; ++u) {
        int n = b * 32 + qs + u;
        long addr = ((long)(n >> 4) * 8 * 64 + cpart + (n & 15)) * 8 + (cglob & 7);
        ctxAqf[addr] = (_Float16)vals[u];
    }
}

// ---------------------------------------------------------------------------
// K4: wc = W @ ctxA. No LDS. grid (128 m-tiles of 64, 16 n-tiles of 128) x 256.
// Wave tile: 16 m x 128 n. K=256 (8 kb of 32). .view-faithful scatter.
// ---------------------------------------------------------------------------
__global__ __launch_bounds__(256) void k4_mfma(const _Float16* __restrict__ Wbf,
                                               const _Float16* __restrict__ ctxAqf,
                                               float* __restrict__ out0) {
    const int t = threadIdx.x;
    const int lane = t & 63, wv = t >> 6;
    const int mb = blockIdx.x * 4 + wv;     // 0..511 (16 d-rows each)
    const int nb0 = blockIdx.y * 8;         // 8 nb groups of 16 n
    const _Float16* abase = Wbf + ((long)mb * 8 * 64 + lane) * 8;
    const _Float16* bbase = ctxAqf + ((long)nb0 * 8 * 64 + lane) * 8;

    f32x4 acc[8];
#pragma unroll
    for (int j = 0; j < 8; ++j) acc[j] = (f32x4){0.f, 0.f, 0.f, 0.f};

#pragma unroll
    for (int kb = 0; kb < 8; ++kb) {
        f16x8 af = *(const f16x8*)(abase + (long)kb * 512);
#pragma unroll
        for (int j = 0; j < 8; ++j) {
            f16x8 bf = *(const f16x8*)(bbase + (long)(j * 8 + kb) * 512);
            acc[j] = __builtin_amdgcn_mfma_f32_16x16x32_f16(af, bf, acc[j], 0, 0, 0);
        }
    }
    const int quad = lane >> 4, col = lane & 15;
#pragma unroll
    for (int j = 0; j < 8; ++j) {
        const int n = (nb0 + j) * 16 + col;
        float* ob = out0 + (long)(n >> 5) * 262144 + (n & 31);
#pragma unroll
        for (int rg = 0; rg < 4; ++rg) {
            const int d = mb * 16 + quad * 4 + rg;
            ob[(long)((d >> 3) & 31) * 8192 + (long)(d >> 8) * 256 + (long)(d & 7) * 32] = acc[j][rg];
        }
    }
}

// ---------------------------------------------------------------------------
extern "C" void kernel_launch(void* const* d_in, const int* in_sizes, int n_in,
                              void* d_out, int out_size, void* d_ws, size_t ws_size,
                              hipStream_t stream) {
    const float* inp = (const float*)d_in[0];
    const float* ctx = (const float*)d_in[1];
    const float* Wm  = (const float*)d_in[2];
    float* out0 = (float*)d_out;
    float* out1 = out0 + 16777216;

    float* wsf = (float*)d_ws;
    float* tWpart = wsf;                                   // ZK*2048*256 = 4,194,304 f (16 MB)
    _Float16* hb = (_Float16*)(wsf + 4194304);
    _Float16* Wth    = hb;                                 // 2,097,152 halfs (4 MB)
    _Float16* Wtl    = Wth + 2097152;                      // 4 MB
    _Float16* Wbf    = Wtl + 2097152;                      // 4 MB
    _Float16* ctxAqf = Wbf + 2097152;                      // 1 MB

    hipLaunchKernelGGL(k0_prep, dim3(256), dim3(256), 0, stream, Wm, Wth, Wtl, Wbf);
    hipLaunchKernelGGL(k1_mfma, dim3(64, ZK), dim3(256), 0, stream, inp, Wth, Wtl, tWpart);
    hipLaunchKernelGGL(k2_logits_softmax, dim3(8, 64), dim3(256), 0, stream, tWpart, ctx, out1);
    hipLaunchKernelGGL(k3_ctxA, dim3(8, 64), dim3(256), 0, stream, ctx, out1, ctxAqf);
    hipLaunchKernelGGL(k4_mfma, dim3(128, 16), dim3(256), 0, stream, Wbf, ctxAqf, out0);
}

// Round 5
// 230.479 us; speedup vs baseline: 1.2039x; 1.2039x over previous
//
#include <hip/hip_runtime.h>
#include <math.h>

// B=64, CLN=32, QL=32, IH=16, IW=16, IDF=8192, CDF=256, SL=128
// input : [64][32][32][16][16] fp32 ; context:[64][256][128] fp32 ; W:[8192][256] fp32
// out0: wc fp32 (16777216) ; out1: attnT [64][128][32] fp32 (262144)
//
// Zero-LDS MFMA pipeline, frag-major pre-swizzled operands.
// k1: fp16 hi/lo 3-pass, register double-buffered, 128m x 256n blocks, ZK=16.
// Order: k0a (Wth/Wtl) -> k1 -> k2 -> k0b (Wbf, overlaid) -> k3 -> k4.

#define ZK 16

typedef _Float16 f16x8 __attribute__((ext_vector_type(8)));
typedef float f32x4 __attribute__((ext_vector_type(4)));

// ---------------------------------------------------------------------------
// K0a: W -> Wth/Wtl (k1 B-operand hi/lo, frag-major). grid(256) x 256 thr.
// Frag addr: ((kb*16+nsub)*64 + lane)*8 ; lane=(c&15)+16*((k>>3)&3), j=k&7
// ---------------------------------------------------------------------------
__global__ __launch_bounds__(256) void k0a_prep(const float* __restrict__ Wm,
                                                _Float16* __restrict__ Wth,
                                                _Float16* __restrict__ Wtl) {
    const int kb = blockIdx.x;          // 0..255 (32 d-rows)
    const int t = threadIdx.x;
    __shared__ float tile[32][260];
    {
        const int r = t >> 3;           // 0..31
        const int c0 = (t & 7) * 32;    // 0..224
        const float* src = Wm + (long)(kb * 32 + r) * 256 + c0;
#pragma unroll
        for (int i = 0; i < 8; ++i) {
            float4 v = *(const float4*)(src + i * 4);
            tile[r][c0 + i * 4 + 0] = v.x;
            tile[r][c0 + i * 4 + 1] = v.y;
            tile[r][c0 + i * 4 + 2] = v.z;
            tile[r][c0 + i * 4 + 3] = v.w;
        }
    }
    __syncthreads();
    const int lane = t & 63;
    const int quad = lane >> 4, l15 = lane & 15;
#pragma unroll
    for (int i = 0; i < 4; ++i) {
        int nsub = (t >> 6) * 4 + i;    // 0..15
        f16x8 oh, ol;
#pragma unroll
        for (int j = 0; j < 8; ++j) {
            float f = tile[quad * 8 + j][nsub * 16 + l15];
            _Float16 h = (_Float16)f;
            oh[j] = h;
            ol[j] = (_Float16)(f - (float)h);
        }
        long addr = ((long)(kb * 16 + nsub) * 64 + lane) * 8;
        *(f16x8*)(Wth + addr) = oh;
        *(f16x8*)(Wtl + addr) = ol;
    }
}

// ---------------------------------------------------------------------------
// K0b: W -> Wbf (k4 A-operand fp16, frag-major). grid(1024) x 256 thr.
// Frag addr: ((mb*8+kb4)*64+lane)*8 ; lane=(d&15)+16*((c>>3)&3), j=c&7
// ---------------------------------------------------------------------------
__global__ __launch_bounds__(256) void k0b_prep(const float* __restrict__ Wm,
                                                _Float16* __restrict__ Wbf) {
    const int t = threadIdx.x;
    const int fid = blockIdx.x * 4 + (t >> 6);   // 0..4095
    const int mb = fid >> 3, kb4 = fid & 7;
    const int lane = t & 63;
    const int quad = lane >> 4, l15 = lane & 15;
    const float* src = Wm + (long)(mb * 16 + l15) * 256 + kb4 * 32 + quad * 8;
    float4 u0 = *(const float4*)(src);
    float4 u1 = *(const float4*)(src + 4);
    f16x8 o;
    o[0] = (_Float16)u0.x; o[1] = (_Float16)u0.y;
    o[2] = (_Float16)u0.z; o[3] = (_Float16)u0.w;
    o[4] = (_Float16)u1.x; o[5] = (_Float16)u1.y;
    o[6] = (_Float16)u1.z; o[7] = (_Float16)u1.w;
    *(f16x8*)(Wbf + ((long)fid * 64 + lane) * 8) = o;
}

// ---------------------------------------------------------------------------
// K1: tWpart = targetT @ W, fp16 hi/lo 3-pass, register double-buffered.
// grid (16 m-tiles of 128, ZK=16) x 512 thr (8 waves, wave tile 64m x 64n).
// No LDS, no barriers. K per block = 512 (16 iters of BK=32).
// ---------------------------------------------------------------------------
__global__ __launch_bounds__(512, 2) void k1_mfma(const float* __restrict__ inp,
                                                  const _Float16* __restrict__ Wth,
                                                  const _Float16* __restrict__ Wtl,
                                                  float* __restrict__ tWpart) {
    const int m0 = blockIdx.x * 128;
    const int kz = blockIdx.y;          // 0..15
    const int t = threadIdx.x;
    const int lane = t & 63, wv = t >> 6;
    const int quad = lane >> 4, l15 = lane & 15;
    const int mi = wv >> 2;             // 0..1 -> 4 m-frags each
    const int ni = wv & 3;              // 0..3 -> 4 n-frags each

    const float* arow0;
    const float* arow1;
    const float* arow2;
    const float* arow3;
    {
        int mA = m0 + (mi * 4 + 0) * 16 + l15;
        arow0 = inp + (long)(mA >> 5) * 262144 + (long)(mA & 31) * 256;
        mA = m0 + (mi * 4 + 1) * 16 + l15;
        arow1 = inp + (long)(mA >> 5) * 262144 + (long)(mA & 31) * 256;
        mA = m0 + (mi * 4 + 2) * 16 + l15;
        arow2 = inp + (long)(mA >> 5) * 262144 + (long)(mA & 31) * 256;
        mA = m0 + (mi * 4 + 3) * 16 + l15;
        arow3 = inp + (long)(mA >> 5) * 262144 + (long)(mA & 31) * 256;
    }

    f32x4 acc[4][4];
#pragma unroll
    for (int i = 0; i < 4; ++i)
#pragma unroll
        for (int j = 0; j < 4; ++j) acc[i][j] = (f32x4){0.f, 0.f, 0.f, 0.f};

    float4 Ar[2][4][2];
    f16x8 Bh[2][4], Bl[2][4];

    // prologue: load it=0
    {
        const int k0g = kz * 512;
        const long off = (long)(k0g >> 8) * 8192 + (k0g & 255) + quad * 8;
        Ar[0][0][0] = *(const float4*)(arow0 + off); Ar[0][0][1] = *(const float4*)(arow0 + off + 4);
        Ar[0][1][0] = *(const float4*)(arow1 + off); Ar[0][1][1] = *(const float4*)(arow1 + off + 4);
        Ar[0][2][0] = *(const float4*)(arow2 + off); Ar[0][2][1] = *(const float4*)(arow2 + off + 4);
        Ar[0][3][0] = *(const float4*)(arow3 + off); Ar[0][3][1] = *(const float4*)(arow3 + off + 4);
        const long base = ((long)((kz * 16) * 16 + ni * 4) * 64 + lane) * 8;
#pragma unroll
        for (int j = 0; j < 4; ++j) {
            Bh[0][j] = *(const f16x8*)(Wth + base + (long)j * 512);
            Bl[0][j] = *(const f16x8*)(Wtl + base + (long)j * 512);
        }
    }

#pragma unroll
    for (int it = 0; it < 16; ++it) {
        const int cur = it & 1, nxt = cur ^ 1;
        if (it < 15) {
            const int k0g = kz * 512 + (it + 1) * 32;
            const long off = (long)(k0g >> 8) * 8192 + (k0g & 255) + quad * 8;
            Ar[nxt][0][0] = *(const float4*)(arow0 + off); Ar[nxt][0][1] = *(const float4*)(arow0 + off + 4);
            Ar[nxt][1][0] = *(const float4*)(arow1 + off); Ar[nxt][1][1] = *(const float4*)(arow1 + off + 4);
            Ar[nxt][2][0] = *(const float4*)(arow2 + off); Ar[nxt][2][1] = *(const float4*)(arow2 + off + 4);
            Ar[nxt][3][0] = *(const float4*)(arow3 + off); Ar[nxt][3][1] = *(const float4*)(arow3 + off + 4);
            const long base = ((long)((kz * 16 + it + 1) * 16 + ni * 4) * 64 + lane) * 8;
#pragma unroll
            for (int j = 0; j < 4; ++j) {
                Bh[nxt][j] = *(const f16x8*)(Wth + base + (long)j * 512);
                Bl[nxt][j] = *(const f16x8*)(Wtl + base + (long)j * 512);
            }
        }
        f16x8 ah[4], al[4];
#pragma unroll
        for (int i = 0; i < 4; ++i) {
            float ff[8] = {Ar[cur][i][0].x, Ar[cur][i][0].y, Ar[cur][i][0].z, Ar[cur][i][0].w,
                           Ar[cur][i][1].x, Ar[cur][i][1].y, Ar[cur][i][1].z, Ar[cur][i][1].w};
#pragma unroll
            for (int j = 0; j < 8; ++j) {
                _Float16 h = (_Float16)ff[j];
                ah[i][j] = h;
                al[i][j] = (_Float16)(ff[j] - (float)h);
            }
        }
#pragma unroll
        for (int i = 0; i < 4; ++i)
#pragma unroll
            for (int j = 0; j < 4; ++j) {
                acc[i][j] = __builtin_amdgcn_mfma_f32_16x16x32_f16(ah[i], Bh[cur][j], acc[i][j], 0, 0, 0);
                acc[i][j] = __builtin_amdgcn_mfma_f32_16x16x32_f16(al[i], Bh[cur][j], acc[i][j], 0, 0, 0);
                acc[i][j] = __builtin_amdgcn_mfma_f32_16x16x32_f16(ah[i], Bl[cur][j], acc[i][j], 0, 0, 0);
            }
    }

    float* outp = tWpart + (long)kz * 524288;
#pragma unroll
    for (int i = 0; i < 4; ++i) {
        const int mbase = m0 + (mi * 4 + i) * 16 + quad * 4;
#pragma unroll
        for (int j = 0; j < 4; ++j) {
            const int c = (ni * 4 + j) * 16 + l15;
#pragma unroll
            for (int rg = 0; rg < 4; ++rg)
                outp[(long)(mbase + rg) * 256 + c] = acc[i][j][rg];
        }
    }
}

// ---------------------------------------------------------------------------
// K2: reduce split-K partials; logits = tW @ ctx[b]; softmax; write attnT.
// grid (8 q-groups of 4, 64 b) x 256 thr. One wave per q row.
// ---------------------------------------------------------------------------
__global__ __launch_bounds__(256) void k2_logits_softmax(const float* __restrict__ tWpart,
                                                         const float* __restrict__ ctx,
                                                         float* __restrict__ attnT) {
    const int qg = blockIdx.x;      // 0..7
    const int b  = blockIdx.y;
    const int t  = threadIdx.x;
    __shared__ float tw4[4][256];
#pragma unroll
    for (int qq = 0; qq < 4; ++qq) {
        const float* p = tWpart + (long)(b * 32 + qg * 4 + qq) * 256 + t;
        float s = 0.f;
#pragma unroll
        for (int z = 0; z < ZK; ++z) s += p[(long)z * 524288];
        tw4[qq][t] = s;
    }
    __syncthreads();
    const int q = t >> 6, lane = t & 63;
    const float* ctxb = ctx + (long)b * 32768 + lane * 2;
    float ax = 0.f, ay = 0.f;
#pragma unroll 4
    for (int c = 0; c < 256; ++c) {
        float tw = tw4[q][c];
        float2 cv = *(const float2*)(ctxb + c * 128);
        ax = fmaf(tw, cv.x, ax);
        ay = fmaf(tw, cv.y, ay);
    }
    float mx = fmaxf(ax, ay);
#pragma unroll
    for (int m = 1; m <= 32; m <<= 1) mx = fmaxf(mx, __shfl_xor(mx, m));
    float ex = expf(ax - mx);
    float ey = expf(ay - mx);
    float sm = ex + ey;
#pragma unroll
    for (int m = 1; m <= 32; m <<= 1) sm += __shfl_xor(sm, m);
    float inv = 1.f / sm;
    ex *= inv; ey *= inv;
    float* o = attnT + (long)b * 4096 + (qg * 4 + q);
    o[(lane * 2 + 0) * 32] = ex;
    o[(lane * 2 + 1) * 32] = ey;
}

// ---------------------------------------------------------------------------
// K3: ctxAqf (frag-major fp16) = ctx @ attn. grid (8 c-chunks, 64 b) x 256.
// Frag addr: [((n>>4)*8 + (c>>5))*64 + (n&15) + 16*((c>>3)&3)]*8 + (c&7)
// ---------------------------------------------------------------------------
__global__ __launch_bounds__(256) void k3_ctxA(const float* __restrict__ ctx,
                                               const float* __restrict__ attnT,
                                               _Float16* __restrict__ ctxAqf) {
    const int cg = blockIdx.x;      // c-chunk of 32
    const int b  = blockIdx.y;
    const int t  = threadIdx.x;
    __shared__ float at[128][32];
    __shared__ float cs[32][132];
#pragma unroll
    for (int i = 0; i < 4; ++i)
        *(float4*)((float*)at + i * 1024 + t * 4) =
            *(const float4*)(attnT + (long)b * 4096 + i * 1024 + t * 4);
#pragma unroll
    for (int i = 0; i < 4; ++i) {
        int idx = i * 256 + t;
        int c = idx >> 5, sseg = (idx & 31) * 4;
        *(float4*)&cs[c][sseg] = *(const float4*)(ctx + (long)b * 32768 + (long)(cg * 32 + c) * 128 + sseg);
    }
    __syncthreads();
    const int c = t >> 3;           // 0..31 (local)
    const int qs = (t & 7) * 4;     // 4 q's
    float4 acc = make_float4(0.f, 0.f, 0.f, 0.f);
#pragma unroll 4
    for (int s = 0; s < 128; ++s) {
        float cv = cs[c][s];
        float4 av = *(const float4*)&at[s][qs];
        acc.x = fmaf(cv, av.x, acc.x);
        acc.y = fmaf(cv, av.y, acc.y);
        acc.z = fmaf(cv, av.z, acc.z);
        acc.w = fmaf(cv, av.w, acc.w);
    }
    const int cglob = cg * 32 + c;
    const long cpart = (long)(cglob >> 5) * 64 + 16 * ((cglob >> 3) & 3);
    float vals[4] = {acc.x, acc.y, acc.z, acc.w};
#pragma unroll
    for (int u = 0; u < 4; ++u) {
        int n = b * 32 + qs + u;
        long addr = ((long)(n >> 4) * 8 * 64 + cpart + (n & 15)) * 8 + (cglob & 7);
        ctxAqf[addr] = (_Float16)vals[u];
    }
}

// ---------------------------------------------------------------------------
// K4: wc = W @ ctxA. No LDS. grid (128 m-tiles of 64, 16 n-tiles of 128) x 256.
// Wave tile: 16 m x 128 n. K=256 (8 kb of 32). .view-faithful scatter.
// ---------------------------------------------------------------------------
__global__ __launch_bounds__(256) void k4_mfma(const _Float16* __restrict__ Wbf,
                                               const _Float16* __restrict__ ctxAqf,
                                               float* __restrict__ out0) {
    const int t = threadIdx.x;
    const int lane = t & 63, wv = t >> 6;
    const int mb = blockIdx.x * 4 + wv;     // 0..511 (16 d-rows each)
    const int nb0 = blockIdx.y * 8;         // 8 nb groups of 16 n
    const _Float16* abase = Wbf + ((long)mb * 8 * 64 + lane) * 8;
    const _Float16* bbase = ctxAqf + ((long)nb0 * 8 * 64 + lane) * 8;

    f32x4 acc[8];
#pragma unroll
    for (int j = 0; j < 8; ++j) acc[j] = (f32x4){0.f, 0.f, 0.f, 0.f};

#pragma unroll
    for (int kb = 0; kb < 8; ++kb) {
        f16x8 af = *(const f16x8*)(abase + (long)kb * 512);
#pragma unroll
        for (int j = 0; j < 8; ++j) {
            f16x8 bf = *(const f16x8*)(bbase + (long)(j * 8 + kb) * 512);
            acc[j] = __builtin_amdgcn_mfma_f32_16x16x32_f16(af, bf, acc[j], 0, 0, 0);
        }
    }
    const int quad = lane >> 4, col = lane & 15;
#pragma unroll
    for (int j = 0; j < 8; ++j) {
        const int n = (nb0 + j) * 16 + col;
        float* ob = out0 + (long)(n >> 5) * 262144 + (n & 31);
#pragma unroll
        for (int rg = 0; rg < 4; ++rg) {
            const int d = mb * 16 + quad * 4 + rg;
            ob[(long)((d >> 3) & 31) * 8192 + (long)(d >> 8) * 256 + (long)(d & 7) * 32] = acc[j][rg];
        }
    }
}

// ---------------------------------------------------------------------------
extern "C" void kernel_launch(void* const* d_in, const int* in_sizes, int n_in,
                              void* d_out, int out_size, void* d_ws, size_t ws_size,
                              hipStream_t stream) {
    const float* inp = (const float*)d_in[0];
    const float* ctx = (const float*)d_in[1];
    const float* Wm  = (const float*)d_in[2];
    float* out0 = (float*)d_out;
    float* out1 = out0 + 16777216;

    // Workspace layout (40 MB peak):
    //   [0, 32 MB)   : tWpart (k1->k2); after k2, overlaid by Wbf (4 MB) + ctxAqf (1 MB)
    //   [32, 36 MB)  : Wth
    //   [36, 40 MB)  : Wtl
    float* wsf = (float*)d_ws;
    float* tWpart = wsf;                                   // 16*2048*256 floats = 32 MB
    _Float16* Wbf    = (_Float16*)wsf;                     // overlaid after k2 (4 MB)
    _Float16* ctxAqf = (_Float16*)(wsf + 1048576);         // overlaid after k2 (1 MB)
    _Float16* Wth = (_Float16*)(wsf + 8388608);            // 4 MB
    _Float16* Wtl = Wth + 2097152;                         // 4 MB

    hipLaunchKernelGGL(k0a_prep, dim3(256), dim3(256), 0, stream, Wm, Wth, Wtl);
    hipLaunchKernelGGL(k1_mfma, dim3(16, ZK), dim3(512), 0, stream, inp, Wth, Wtl, tWpart);
    hipLaunchKernelGGL(k2_logits_softmax, dim3(8, 64), dim3(256), 0, stream, tWpart, ctx, out1);
    hipLaunchKernelGGL(k0b_prep, dim3(1024), dim3(256), 0, stream, Wm, Wbf);
    hipLaunchKernelGGL(k3_ctxA, dim3(8, 64), dim3(256), 0, stream, ctx, out1, ctxAqf);
    hipLaunchKernelGGL(k4_mfma, dim3(128, 16), dim3(256), 0, stream, Wbf, ctxAqf, out0);
}